// Round 11
// baseline (209.961 us; speedup 1.0000x reference)
//
#include <hip/hip_runtime.h>
#include <cmath>

#define N_NODES 8192
#define HDIM 256
#define NFRAG 256
#define RMIX 0.3f
#define CSIM 0.8f
#define LN2 0.6931471805599453f
#define CMAX 64          // LDS fast-path row capacity per (fragment, matrix)

typedef __bf16 bf16x8 __attribute__((ext_vector_type(8)));
typedef float f32x4 __attribute__((ext_vector_type(4)));
typedef unsigned short us8 __attribute__((ext_vector_type(8)));
typedef unsigned short us4 __attribute__((ext_vector_type(4)));
typedef unsigned short ushort_t;

// ---- workspace layout (bytes) ----
#define SI_OFF   ((size_t)0)                    // 8192*256*4  = 8 MB
#define VI_OFF   ((size_t)8388608)              // 24576*256*4 = 24 MB
#define WH_OFF   ((size_t)58720256)             // 4 * 65536 * 2 = 524,288
#define WL_OFF   ((size_t)59244544)             // 524,288
#define CNT_OFF  ((size_t)59768832)             // 256 ints
#define CUR_OFF  (CNT_OFF + 1024)
#define OFF_OFF  (CNT_OFF + 2048)
#define SORT_OFF (CNT_OFF + 3072)               // 8192 ints
#define ACC_OFF  (SORT_OFF + 32768)
#define FLG_OFF  (ACC_OFF + 128)
#define NRM_OFF  (ACC_OFF + 256)                // 4 regions x 8192 floats

// ---- bf16 split helpers (RNE) ----
__device__ __forceinline__ ushort_t f2bf(float x) {
    unsigned u = __float_as_uint(x);
    return (ushort_t)((u + 0x7FFFu + ((u >> 16) & 1u)) >> 16);
}
__device__ __forceinline__ float bf2f(ushort_t h) {
    return __uint_as_float(((unsigned)h) << 16);
}
__device__ __forceinline__ f32x4 mfma_bf16(us8 a, us8 b, f32x4 c) {
    return __builtin_amdgcn_mfma_f32_16x16x32_bf16(
        __builtin_bit_cast(bf16x8, a), __builtin_bit_cast(bf16x8, b), c, 0, 0, 0);
}

// fragment_ids layout access: flag=1 -> plain int32; flag=0 -> int64 LE (stride 2)
__device__ __forceinline__ int loadFrag(const int* __restrict__ buf, int flagv, int i) {
    return flagv ? buf[i] : buf[2 * i];
}

// ============================= setup kernels =============================

__global__ void init_kernel(int* counts, int* cursor, float* acc, int* flag) {
    int t = threadIdx.x;
    if (t < NFRAG) { counts[t] = 0; cursor[t] = 0; }
    if (t < 8) acc[t] = 0.f;
    if (t == 0) *flag = 0;
}

// int64 LE -> int32 view is [id,0,id,0,...]: odd positions all zero (ids<256).
__global__ void detect_kernel(const int* __restrict__ buf, int* flag) {
    int i = blockIdx.x * 256 + threadIdx.x;       // 0..4095
    if (buf[2 * i + 1] != 0) atomicOr(flag, 1);   // 1 => plain int32 layout
}

__global__ void hist_kernel(const int* __restrict__ buf, const int* __restrict__ flag,
                            int* counts) {
    int i = blockIdx.x * 256 + threadIdx.x;
    if (i < N_NODES) atomicAdd(&counts[loadFrag(buf, *flag, i)], 1);
}

__global__ void scan_kernel(const int* __restrict__ counts, int* offs) {
    __shared__ int tmp[NFRAG];
    int t = threadIdx.x;
    tmp[t] = counts[t];
    __syncthreads();
    for (int off = 1; off < NFRAG; off <<= 1) {
        int v = (t >= off) ? tmp[t - off] : 0;
        __syncthreads();
        tmp[t] += v;
        __syncthreads();
    }
    offs[t] = tmp[t] - counts[t];   // exclusive scan
}

__global__ void scatter_kernel(const int* __restrict__ buf, const int* __restrict__ flag,
                               const int* __restrict__ offs, int* cursor, int* sorted) {
    int i = blockIdx.x * 256 + threadIdx.x;
    if (i < N_NODES) {
        int f = loadFrag(buf, *flag, i);
        int pos = offs[f] + atomicAdd(&cursor[f], 1);
        sorted[pos] = i;
    }
}

// Split the 4 weight matrices into bf16 hi/lo in MFMA-fragment-native layout:
// dst[((kb*256 + n)*4 + kg)*8 + e] = W[(kb*32 + kg*8 + e)*256 + n]
__global__ void wsplit_kernel(const float* __restrict__ W1, const float* __restrict__ W2,
                              const float* __restrict__ V1, const float* __restrict__ V2,
                              ushort_t* __restrict__ Whi, ushort_t* __restrict__ Wlo) {
    int m = blockIdx.y;
    const float* src = (m == 0) ? W1 : (m == 1) ? W2 : (m == 2) ? V1 : V2;
    ushort_t* dh = Whi + m * 65536;
    ushort_t* dl = Wlo + m * 65536;
    int o = blockIdx.x * 256 + threadIdx.x;   // 0..65535
    int e = o & 7, kg = (o >> 3) & 3, n = (o >> 5) & 255, kb = o >> 13;
    float x = src[(size_t)(kb * 32 + kg * 8 + e) * HDIM + n];
    ushort_t h = f2bf(x);
    dh[o] = h;
    dl[o] = f2bf(x - bf2f(h));
}

// ============================= fused 2-layer MLP, merged branches =============================
// One dispatch for scalar (rows [0,8192)) and vector (rows [8192,32768)).
// Block = 256 thr (4 waves), BM=32 rows, BN=256 full width; split-bf16 4-pass.
// LDS 32 KB (32x256 bf16 hi/lo tile, XOR-swizzled, reused A->T) => with
// __launch_bounds__(256,4): 4 blocks/CU, 16 waves/CU — cross-block overlap
// hides phase0's HBM burst under other blocks' MFMA phases (round-10 lesson:
// BM=64/2-blocks left every pipe <25%).
// Swapped mfma operands (HW-verified rounds 7/9/10, absmax 0.0).

__global__ __launch_bounds__(256, 4)
void mlp_fused_all(const float* __restrict__ s_short, const float* __restrict__ s_long,
                   const float* __restrict__ v_short, const float* __restrict__ v_long,
                   const ushort_t* __restrict__ WH, const ushort_t* __restrict__ WL,
                   const float* __restrict__ b1, const float* __restrict__ b2,
                   float* __restrict__ SI, float* __restrict__ VI)
{
    __shared__ __align__(16) ushort_t Zh[32 * 256];   // 16 KB
    __shared__ __align__(16) ushort_t Zl[32 * 256];   // 16 KB

    const int tid = threadIdx.x;
    const int l   = tid & 63;
    const int wid = tid >> 6;
    const int lr  = l & 15;
    const int kg  = l >> 4;
    const int colW = wid * 64;

    const int rowBase = blockIdx.x * 32;
    const bool isScalar = (rowBase < N_NODES);
    const float* A0;
    const float* A1;
    float* Out;
    const ushort_t *B1h, *B1l, *B2h, *B2l;
    if (isScalar) {
        size_t off = (size_t)rowBase * HDIM;
        A0 = s_short + off;  A1 = s_long + off;  Out = SI + off;
        B1h = WH;              B1l = WL;
        B2h = WH + 65536;      B2l = WL + 65536;
    } else {
        size_t off = (size_t)(rowBase - N_NODES) * HDIM;
        A0 = v_short + off;  A1 = v_long + off;  Out = VI + off;
        B1h = WH + 2 * 65536;  B1l = WL + 2 * 65536;
        B2h = WH + 3 * 65536;  B2l = WL + 3 * 65536;
    }

    // ---- phase 0: coalesced load + mix + split -> LDS (32 elems/thread) ----
    {
        int r  = tid >> 3;               // 0..31 local row
        int c0 = (tid & 7) * 32;         // 32-float run
        const float* ps = A0 + (size_t)r * HDIM + c0;
        const float* pl = A1 + (size_t)r * HDIM + c0;
        int swz = (r & 7) << 3;
        #pragma unroll
        for (int cc = 0; cc < 4; ++cc) {
            float4 s0 = *(const float4*)(ps + cc * 8);
            float4 s1 = *(const float4*)(ps + cc * 8 + 4);
            float4 t0 = *(const float4*)(pl + cc * 8);
            float4 t1 = *(const float4*)(pl + cc * 8 + 4);
            float x[8];
            x[0] = s0.x * RMIX + t0.x * (1.f - RMIX);
            x[1] = s0.y * RMIX + t0.y * (1.f - RMIX);
            x[2] = s0.z * RMIX + t0.z * (1.f - RMIX);
            x[3] = s0.w * RMIX + t0.w * (1.f - RMIX);
            x[4] = s1.x * RMIX + t1.x * (1.f - RMIX);
            x[5] = s1.y * RMIX + t1.y * (1.f - RMIX);
            x[6] = s1.z * RMIX + t1.z * (1.f - RMIX);
            x[7] = s1.w * RMIX + t1.w * (1.f - RMIX);
            us8 h, lo;
            #pragma unroll
            for (int e = 0; e < 8; ++e) {
                ushort_t hh = f2bf(x[e]);
                h[e] = hh;
                lo[e] = f2bf(x[e] - bf2f(hh));
            }
            int idx = r * 256 + ((c0 + cc * 8) ^ swz);
            *(us8*)&Zh[idx] = h;
            *(us8*)&Zl[idx] = lo;
        }
    }
    __syncthreads();

    // lane-level W base: offset = (colW+lr)*32 + kg*8; +nf*512 imm; +kb*8192 step
    const int wbase = (colW + lr) * 32 + kg * 8;

    // ---- phase 1: acc = mix @ W1 ----
    f32x4 acc[2][4];
    #pragma unroll
    for (int mf = 0; mf < 2; ++mf)
        #pragma unroll
        for (int nf = 0; nf < 4; ++nf)
            acc[mf][nf] = f32x4{0.f, 0.f, 0.f, 0.f};

    {
        const ushort_t* ph = B1h + wbase;
        const ushort_t* pl = B1l + wbase;
        for (int kb = 0; kb < 8; ++kb) {
            const int kx = kb * 32 + kg * 8;
            us8 ah[2], al[2];
            #pragma unroll
            for (int mf = 0; mf < 2; ++mf) {
                int m = mf * 16 + lr;
                int idx = m * 256 + (kx ^ ((m & 7) << 3));
                ah[mf] = *(const us8*)&Zh[idx];
                al[mf] = *(const us8*)&Zl[idx];
            }
            #pragma unroll
            for (int nf = 0; nf < 4; ++nf) {
                us8 wh = *(const us8*)(ph + nf * 512);
                us8 wl = *(const us8*)(pl + nf * 512);
                #pragma unroll
                for (int mf = 0; mf < 2; ++mf) {
                    f32x4 t = acc[mf][nf];
                    t = mfma_bf16(wl, al[mf], t);
                    t = mfma_bf16(wl, ah[mf], t);
                    t = mfma_bf16(wh, al[mf], t);
                    t = mfma_bf16(wh, ah[mf], t);
                    acc[mf][nf] = t;
                }
            }
            ph += 8192; pl += 8192;
        }
    }
    __syncthreads();   // all waves done reading A tile

    // ---- layer-1 epilogue: bias + SSP, split, T -> LDS (overwrites A) ----
    #pragma unroll
    for (int mf = 0; mf < 2; ++mf) {
        int m = mf * 16 + lr;
        #pragma unroll
        for (int nf = 0; nf < 4; ++nf) {
            int n0 = colW + nf * 16 + kg * 4;
            float4 bb = {0.f, 0.f, 0.f, 0.f};
            if (isScalar) bb = *(const float4*)(b1 + n0);
            us4 h4, l4;
            #pragma unroll
            for (int r = 0; r < 4; ++r) {
                float x = acc[mf][nf][r] + ((const float*)&bb)[r];
                // ssp via __logf/__expf: T's split-bf16 representation error
                // (~2^-17 rel) dominates the ~1e-7 approximation error.
                x = fmaxf(x, 0.f) + __logf(1.f + __expf(-fabsf(x))) - LN2;
                ushort_t hh = f2bf(x);
                h4[r] = hh;
                l4[r] = f2bf(x - bf2f(hh));
            }
            int idx = m * 256 + (n0 ^ ((m & 7) << 3));
            *(us4*)&Zh[idx] = h4;
            *(us4*)&Zl[idx] = l4;
        }
    }
    __syncthreads();

    // ---- phase 2: acc2 = T @ W2 ----
    f32x4 acc2[2][4];
    #pragma unroll
    for (int mf = 0; mf < 2; ++mf)
        #pragma unroll
        for (int nf = 0; nf < 4; ++nf)
            acc2[mf][nf] = f32x4{0.f, 0.f, 0.f, 0.f};

    {
        const ushort_t* ph = B2h + wbase;
        const ushort_t* pl = B2l + wbase;
        for (int kb = 0; kb < 8; ++kb) {
            const int kx = kb * 32 + kg * 8;
            us8 ah[2], al[2];
            #pragma unroll
            for (int mf = 0; mf < 2; ++mf) {
                int m = mf * 16 + lr;
                int idx = m * 256 + (kx ^ ((m & 7) << 3));
                ah[mf] = *(const us8*)&Zh[idx];
                al[mf] = *(const us8*)&Zl[idx];
            }
            #pragma unroll
            for (int nf = 0; nf < 4; ++nf) {
                us8 wh = *(const us8*)(ph + nf * 512);
                us8 wl = *(const us8*)(pl + nf * 512);
                #pragma unroll
                for (int mf = 0; mf < 2; ++mf) {
                    f32x4 t = acc2[mf][nf];
                    t = mfma_bf16(wl, al[mf], t);
                    t = mfma_bf16(wl, ah[mf], t);
                    t = mfma_bf16(wh, al[mf], t);
                    t = mfma_bf16(wh, ah[mf], t);
                    acc2[mf][nf] = t;
                }
            }
            ph += 8192; pl += 8192;
        }
    }

    // ---- final epilogue: bias2 (scalar branch), float4 store ----
    #pragma unroll
    for (int mf = 0; mf < 2; ++mf) {
        int m = mf * 16 + lr;
        #pragma unroll
        for (int nf = 0; nf < 4; ++nf) {
            int n0 = colW + nf * 16 + kg * 4;
            float4 bb = {0.f, 0.f, 0.f, 0.f};
            if (isScalar) bb = *(const float4*)(b2 + n0);
            float4 v;
            v.x = acc2[mf][nf][0] + bb.x;
            v.y = acc2[mf][nf][1] + bb.y;
            v.z = acc2[mf][nf][2] + bb.z;
            v.w = acc2[mf][nf][3] + bb.w;
            *(float4*)(Out + (size_t)m * HDIM + n0) = v;
        }
    }
}

// ============================= fragment statistics =============================

__device__ __forceinline__ float blockReduceSum(float v, float* red) {
    #pragma unroll
    for (int off = 32; off > 0; off >>= 1)
        v += __shfl_down(v, off, 64);
    __syncthreads();
    if ((threadIdx.x & 63) == 0) red[threadIdx.x >> 6] = v;
    __syncthreads();
    return red[0] + red[1] + red[2] + red[3];
}

__device__ __forceinline__ float dot4(float4 a, float4 b) {
    return a.x * b.x + a.y * b.y + a.z * b.z + a.w * b.w;
}

__device__ void compute_invn_g(const float* __restrict__ Mat, int mult, int doff,
                               int c, int basep, const int* __restrict__ sorted,
                               float* invn, int tid)
{
    for (int p = tid; p < c; p += 256) {
        int nd = sorted[basep + p];
        const float4* row = (const float4*)(Mat + ((size_t)nd * mult + doff) * HDIM);
        float ss = 0.f;
        #pragma unroll 8
        for (int k = 0; k < 64; ++k) {
            float4 v = row[k];
            ss += v.x * v.x + v.y * v.y + v.z * v.z + v.w * v.w;
        }
        invn[p] = 1.0f / fmaxf(sqrtf(ss), 1e-12f);
    }
}

__device__ float pair_err_slow(const float* __restrict__ Mat, int mult, int doff,
                               int c, int basep, const int* __restrict__ sorted,
                               const float* invn, int tid)
{
    float e = 0.f;
    for (long pi = tid; pi < (long)c * c; pi += 256) {
        int i = (int)(pi / c), j = (int)(pi - (long)i * c);
        if (j <= i) continue;
        const float4* ri = (const float4*)(Mat + ((size_t)sorted[basep + i] * mult + doff) * HDIM);
        const float4* rj = (const float4*)(Mat + ((size_t)sorted[basep + j] * mult + doff) * HDIM);
        float dt = 0.f;
        for (int k = 0; k < 64; ++k) dt += dot4(ri[k], rj[k]);
        float sv = dt * invn[i] * invn[j];
        float d = sv - CSIM;
        e += d * d;
    }
    return e;
}

// One block per (fragment f, matrix m): m=0 -> SI, m=1..3 -> VI dim m-1.
__global__ __launch_bounds__(256)
void fragmat_kernel(const float* __restrict__ SI, const float* __restrict__ VI,
                    const int* __restrict__ counts, const int* __restrict__ offs,
                    const int* __restrict__ sorted, float* acc, float* nrm_global)
{
    const int f = blockIdx.x, m = blockIdx.y, tid = threadIdx.x;
    const int c = counts[f];
    if (c < 2) return;                      // invalid fragment: no contribution
    const int basep = offs[f];
    const float* Mat = (m == 0) ? SI : VI;
    const int mult = (m == 0) ? 1 : 3;
    const int doff = (m == 0) ? 0 : (m - 1);

    __shared__ __align__(16) float Z[CMAX * 260];   // 65 KB
    __shared__ float invn_s[CMAX];
    __shared__ float red[4];

    float var, err;

    if (c <= CMAX) {
        for (int u = tid; u < c * 64; u += 256) {
            int r = u >> 6, kc = u & 63;
            float4 v = *((const float4*)(Mat + ((size_t)sorted[basep + r] * mult + doff) * HDIM) + kc);
            *(float4*)&Z[r * 260 + (kc << 2)] = v;
        }
        __syncthreads();

        float msum = 0.f;
        for (int p = 0; p < c; ++p) msum += Z[p * 260 + tid];
        float mean = msum / (float)c;
        float vh = 0.f;
        for (int p = 0; p < c; ++p) {
            float d = Z[p * 260 + tid] - mean;
            vh += d * d;
        }
        var = blockReduceSum(vh, red);

        for (int p = tid; p < c; p += 256) {
            const float4* row = (const float4*)&Z[p * 260];
            float ss = 0.f;
            #pragma unroll 8
            for (int k = 0; k < 64; ++k) {
                float4 v = row[k];
                ss += v.x * v.x + v.y * v.y + v.z * v.z + v.w * v.w;
            }
            invn_s[p] = 1.0f / fmaxf(sqrtf(ss), 1e-12f);
        }
        __syncthreads();

        const int nb2 = (c + 1) >> 1;
        const int nbp = nb2 * (nb2 + 1) / 2;
        float e = 0.f;
        for (int u = tid; u < nbp; u += 256) {
            int bi = 0, rem = u;
            while (rem >= nb2 - bi) { rem -= nb2 - bi; ++bi; }
            int bj = bi + rem;
            int i0 = bi << 1, j0 = bj << 1;
            const float* zi0 = &Z[i0 * 260];
            const float* zi1 = &Z[(i0 + 1) * 260];
            const float* zj0 = &Z[j0 * 260];
            const float* zj1 = &Z[(j0 + 1) * 260];
            float s00 = 0.f, s01 = 0.f, s10 = 0.f, s11 = 0.f;
            #pragma unroll 4
            for (int k = 0; k < 64; ++k) {
                float4 a0 = *(const float4*)(zi0 + (k << 2));
                float4 a1 = *(const float4*)(zi1 + (k << 2));
                float4 b0 = *(const float4*)(zj0 + (k << 2));
                float4 b1 = *(const float4*)(zj1 + (k << 2));
                s00 += dot4(a0, b0);
                s01 += dot4(a0, b1);
                s10 += dot4(a1, b0);
                s11 += dot4(a1, b1);
            }
            int i1 = i0 + 1, j1 = j0 + 1;
            if (j0 > i0 && j0 < c) { float sv = s00 * invn_s[i0] * invn_s[j0] - CSIM; e += sv * sv; }
            if (j1 > i0 && j1 < c) { float sv = s01 * invn_s[i0] * invn_s[j1] - CSIM; e += sv * sv; }
            if (j0 > i1 && j0 < c) { float sv = s10 * invn_s[i1] * invn_s[j0] - CSIM; e += sv * sv; }
            if (j1 > i1 && j1 < c) { float sv = s11 * invn_s[i1] * invn_s[j1] - CSIM; e += sv * sv; }
        }
        err = blockReduceSum(e, red);
    } else {
        float msum = 0.f;
        for (int p = 0; p < c; ++p)
            msum += Mat[((size_t)sorted[basep + p] * mult + doff) * HDIM + tid];
        float mean = msum / (float)c;
        float vh = 0.f;
        for (int p = 0; p < c; ++p) {
            float d = Mat[((size_t)sorted[basep + p] * mult + doff) * HDIM + tid] - mean;
            vh += d * d;
        }
        var = blockReduceSum(vh, red);

        float* invn = nrm_global + (size_t)m * N_NODES + basep;
        compute_invn_g(Mat, mult, doff, c, basep, sorted, invn, tid);
        __syncthreads();
        float e = pair_err_slow(Mat, mult, doff, c, basep, sorted, invn, tid);
        err = blockReduceSum(e, red);
    }

    if (tid == 0) {
        float n = (float)c;
        float pc = 0.5f * n * (n - 1.f);
        float w_err = (m == 0) ? (0.5f / pc) : (0.5f / (3.f * pc));
        float contrib = 0.5f * var / n + err * w_err;
        atomicAdd(&acc[0], contrib);
        if (m == 0) atomicAdd(&acc[1], 1.0f);
    }
}

__global__ void finalize_kernel(const float* __restrict__ acc, float* __restrict__ out) {
    if (threadIdx.x == 0)
        out[0] = (acc[1] > 0.f) ? acc[0] / acc[1] : 0.f;
}

// ============================= launch =============================

extern "C" void kernel_launch(void* const* d_in, const int* in_sizes, int n_in,
                              void* d_out, int out_size, void* d_ws, size_t ws_size,
                              hipStream_t stream) {
    const float* s_short = (const float*)d_in[0];
    const float* s_long  = (const float*)d_in[1];
    const float* v_short = (const float*)d_in[2];
    const float* v_long  = (const float*)d_in[3];
    const float* W1 = (const float*)d_in[4];
    const float* b1 = (const float*)d_in[5];
    const float* W2 = (const float*)d_in[6];
    const float* b2 = (const float*)d_in[7];
    const float* V1 = (const float*)d_in[8];
    const float* V2 = (const float*)d_in[9];
    const int* fragRaw = (const int*)d_in[10];
    float* out = (float*)d_out;

    char* ws = (char*)d_ws;
    float*    SI     = (float*)(ws + SI_OFF);
    float*    VI     = (float*)(ws + VI_OFF);
    ushort_t* WH     = (ushort_t*)(ws + WH_OFF);
    ushort_t* WL     = (ushort_t*)(ws + WL_OFF);
    int*      counts = (int*)(ws + CNT_OFF);
    int*      cursor = (int*)(ws + CUR_OFF);
    int*      offs   = (int*)(ws + OFF_OFF);
    int*      sorted = (int*)(ws + SORT_OFF);
    float*    acc    = (float*)(ws + ACC_OFF);
    int*      flag   = (int*)(ws + FLG_OFF);
    float*    nrm    = (float*)(ws + NRM_OFF);

    init_kernel<<<1, 256, 0, stream>>>(counts, cursor, acc, flag);
    detect_kernel<<<16, 256, 0, stream>>>(fragRaw, flag);
    hist_kernel<<<N_NODES / 256, 256, 0, stream>>>(fragRaw, flag, counts);
    scan_kernel<<<1, 256, 0, stream>>>(counts, offs);
    scatter_kernel<<<N_NODES / 256, 256, 0, stream>>>(fragRaw, flag, offs, cursor, sorted);
    wsplit_kernel<<<dim3(256, 4), 256, 0, stream>>>(W1, W2, V1, V2, WH, WL);

    // both MLP branches in one dispatch: 1024 blocks of 32 rows (4 blocks/CU)
    mlp_fused_all<<<dim3((N_NODES + 3 * N_NODES) / 32), 256, 0, stream>>>(
        s_short, s_long, v_short, v_long, WH, WL, b1, b2, SI, VI);

    fragmat_kernel<<<dim3(NFRAG, 4), 256, 0, stream>>>(SI, VI, counts, offs, sorted, acc, nrm);
    finalize_kernel<<<1, 64, 0, stream>>>(acc, out);
}